// Round 8
// baseline (183.521 us; speedup 1.0000x reference)
//
#include <hip/hip_runtime.h>
#include <math.h>

// CausalSelfAttention: B=2, T=2048, C=1024, H=16, Dh=64. fp32 in/out.
// GEMM operands in 16x16x32 FRAGMENT-NATIVE layouts  F[i/16][k/8][i%16][8]
// Attention operands in 32x32x16 fragment-native layouts:
//   Q/K: [bh][t/32][d/16][(t%32)+32*((d%16)/8)][d%8]
//   V^T: [bh][d/32][t/16][(d%32)+32*((t%16)/8)][t%8]
//  1. pack_all: x -> x' frag; Wqkv/Wproj -> W' frag (transposed)
//  2. gemm_lds<0>: qkv GEMM, BK=32 double-buffered LDS, distance-2 prefetch,
//     raw s_barrier + counted vmcnt (never drains mid-loop) -> Q'/K'/V'
//  3. attn_mfma: flash attention, DIAGONAL PHASE-PAIRED blocks: each block
//     runs strip-group {4m..4m+3} then mirror {60-4m..63-4m} = exactly 34
//     tile-iters for EVERY block; 256 blocks = 1/CU -> zero tail by
//     construction. LDS-shared K/V double-buffer, counted vmcnt, reg-P.
//  4. gemm_lds<1>: proj GEMM -> out fp32

typedef __attribute__((ext_vector_type(8))) short short8;
typedef __attribute__((ext_vector_type(4))) short short4v;
typedef __attribute__((ext_vector_type(4))) float floatx4;
typedef __attribute__((ext_vector_type(16))) float floatx16;
typedef __attribute__((ext_vector_type(2))) unsigned int uint2v;
typedef __attribute__((ext_vector_type(4))) unsigned int uint4v;

__device__ __forceinline__ unsigned short f2bf(float f) {
  unsigned u = __float_as_uint(f);
  return (unsigned short)((u + 0x7fff + ((u >> 16) & 1)) >> 16);
}

// v_cvt_pk_bf16_f32: dst = {lo: bf16(a), hi: bf16(b)} (RNE)
__device__ __forceinline__ unsigned cvtpk(float a, float b) {
  unsigned r;
  asm("v_cvt_pk_bf16_f32 %0, %1, %2" : "=v"(r) : "v"(a), "v"(b));
  return r;
}

__device__ __forceinline__ short8 mk8(unsigned w0, unsigned w1, unsigned w2,
                                      unsigned w3) {
  uint4v v = {w0, w1, w2, w3};
  return __builtin_bit_cast(short8, v);
}

// async global->LDS, 16B per lane; LDS dst is wave-uniform base + lane*16
__device__ __forceinline__ void gld16(const unsigned short* g, unsigned short* l) {
  __builtin_amdgcn_global_load_lds(
      (const __attribute__((address_space(1))) unsigned int*)g,
      (__attribute__((address_space(3))) unsigned int*)l, 16, 0, 0);
}

__device__ __forceinline__ void vmcnt4() {
  asm volatile("s_waitcnt vmcnt(4)" ::: "memory");
}
__device__ __forceinline__ void vmcnt0() {
  asm volatile("s_waitcnt vmcnt(0)" ::: "memory");
}

// ---------------- fused pack kernel ----------------
__device__ __forceinline__ void pack_a_body(const float* __restrict__ in,
                                            unsigned short* __restrict__ out,
                                            int K, int m0, int k0,
                                            unsigned short (*lds)[72], int t) {
  {
    int ml = t >> 2, kl = (t & 3) * 16;
    const float4* p = (const float4*)(in + (size_t)(m0 + ml) * K + k0 + kl);
    unsigned short* q = &lds[ml][kl];
#pragma unroll
    for (int c = 0; c < 4; ++c) {
      float4 v = p[c];
      q[c * 4 + 0] = f2bf(v.x);
      q[c * 4 + 1] = f2bf(v.y);
      q[c * 4 + 2] = f2bf(v.z);
      q[c * 4 + 3] = f2bf(v.w);
    }
  }
  __syncthreads();
  int chunk = t >> 3, sub = t & 7;
  int mt = chunk >> 3, kc = chunk & 7;
  unsigned short tmp[16];
#pragma unroll
  for (int j2 = 0; j2 < 2; ++j2)
#pragma unroll
    for (int j = 0; j < 8; ++j)
      tmp[j2 * 8 + j] = lds[mt * 16 + sub * 2 + j2][kc * 8 + j];
  size_t ofs = ((size_t)(m0 >> 4) + mt) * (16 * (size_t)K) +
               ((size_t)(k0 >> 3) + kc) * 128 + sub * 16;
  *(int4*)(out + ofs) = *(int4*)(tmp);
  *(int4*)(out + ofs + 8) = *(int4*)(tmp + 8);
}

__device__ __forceinline__ void pack_bt_body(const float* __restrict__ in,
                                             unsigned short* __restrict__ out,
                                             int K, int N, int n0, int k0,
                                             unsigned short (*lds)[72], int t) {
  {
    int kl = t >> 2, nl = (t & 3) * 16;
    const float4* p = (const float4*)(in + (size_t)(k0 + kl) * N + n0 + nl);
#pragma unroll
    for (int c = 0; c < 4; ++c) {
      float4 v = p[c];
      lds[nl + c * 4 + 0][kl] = f2bf(v.x);
      lds[nl + c * 4 + 1][kl] = f2bf(v.y);
      lds[nl + c * 4 + 2][kl] = f2bf(v.z);
      lds[nl + c * 4 + 3][kl] = f2bf(v.w);
    }
  }
  __syncthreads();
  int chunk = t >> 3, sub = t & 7;
  int nt = chunk >> 3, kc = chunk & 7;
  unsigned short tmp[16];
#pragma unroll
  for (int j2 = 0; j2 < 2; ++j2)
#pragma unroll
    for (int j = 0; j < 8; ++j)
      tmp[j2 * 8 + j] = lds[nt * 16 + sub * 2 + j2][kc * 8 + j];
  size_t ofs = ((size_t)(n0 >> 4) + nt) * (16 * (size_t)K) +
               ((size_t)(k0 >> 3) + kc) * 128 + sub * 16;
  *(int4*)(out + ofs) = *(int4*)(tmp);
  *(int4*)(out + ofs + 8) = *(int4*)(tmp + 8);
}

__global__ __launch_bounds__(256) void pack_all(
    const float* __restrict__ x, const float* __restrict__ Wqkv,
    const float* __restrict__ Wproj, unsigned short* __restrict__ xbf,
    unsigned short* __restrict__ wqkvF, unsigned short* __restrict__ wprojF) {
  __shared__ __align__(16) unsigned short lds[64][72];
  const int b = blockIdx.x, t = threadIdx.x;
  if (b < 1024) {
    pack_a_body(x, xbf, 1024, (b >> 4) * 64, (b & 15) * 64, lds, t);
  } else if (b < 1792) {
    int b2 = b - 1024;
    pack_bt_body(Wqkv, wqkvF, 1024, 3072, (b2 % 48) * 64, (b2 / 48) * 64, lds, t);
  } else {
    int b3 = b - 1792;
    pack_bt_body(Wproj, wprojF, 1024, 1024, (b3 & 15) * 64, (b3 >> 4) * 64, lds, t);
  }
}

// ------ LDS double-buffered fragment GEMM (BK=32, distance-2 prefetch) ------
template <int MODE>
__global__ __launch_bounds__(256, 3) void gemm_lds(
    const unsigned short* __restrict__ A, const unsigned short* __restrict__ B,
    const float* __restrict__ bias, float* __restrict__ Cout,
    unsigned short* __restrict__ Qb, unsigned short* __restrict__ Kb,
    unsigned short* __restrict__ Vt, int M, int N, int K) {
  const int tid = threadIdx.x;
  const int wave = tid >> 6, lane = tid & 63;
  const int quad = lane >> 4, l15 = lane & 15;
  const int wr = wave >> 1, wc = wave & 1;

  const int nbn = N >> 7;
  const int colsPerX = nbn >> 3;
  const int xcd = (int)(blockIdx.x & 7);
  const int idx = (int)(blockIdx.x >> 3);
  const int bn = xcd * colsPerX + (colsPerX == 1 ? 0 : (idx % colsPerX));
  const int bm = (colsPerX == 1) ? idx : (idx / colsPerX);

  const int mt0 = bm * 8;
  const int nt0 = bn * 8;

  __shared__ __align__(16) unsigned short As[2][4096];
  __shared__ __align__(16) unsigned short Bs[2][4096];

  const unsigned short* spA[2];
  const unsigned short* spB[2];
#pragma unroll
  for (int jj = 0; jj < 2; ++jj) {
    spA[jj] = A + ((size_t)(mt0 + wave * 2 + jj)) * (16 * (size_t)K) + lane * 8;
    spB[jj] = B + ((size_t)(nt0 + wave * 2 + jj)) * (16 * (size_t)K) + lane * 8;
  }

  floatx4 acc[4][4];
#pragma unroll
  for (int i = 0; i < 4; ++i)
#pragma unroll
    for (int j = 0; j < 4; ++j) acc[i][j] = (floatx4)0.0f;

  const int fofs = quad * 128 + l15 * 8;
  const int nk = K >> 5;  // 32

#pragma unroll
  for (int jj = 0; jj < 2; ++jj) {
    gld16(spA[jj], &As[0][(wave * 2 + jj) * 512]);
    gld16(spB[jj], &Bs[0][(wave * 2 + jj) * 512]);
    spA[jj] += 512;
    spB[jj] += 512;
  }
#pragma unroll
  for (int jj = 0; jj < 2; ++jj) {
    gld16(spA[jj], &As[1][(wave * 2 + jj) * 512]);
    gld16(spB[jj], &Bs[1][(wave * 2 + jj) * 512]);
    spA[jj] += 512;
    spB[jj] += 512;
  }

  for (int kk = 0; kk < nk; ++kk) {
    if (kk + 1 < nk) vmcnt4(); else vmcnt0();
    __builtin_amdgcn_s_barrier();
    __builtin_amdgcn_sched_barrier(0);

    const unsigned short* Ab = As[kk & 1];
    const unsigned short* Bb = Bs[kk & 1];
    short8 fa[4], fb[4];
#pragma unroll
    for (int im = 0; im < 4; ++im)
      fa[im] = *(const short8*)&Ab[(wr * 4 + im) * 512 + fofs];
#pragma unroll
    for (int in = 0; in < 4; ++in)
      fb[in] = *(const short8*)&Bb[(wc * 4 + in) * 512 + fofs];
#pragma unroll
    for (int im = 0; im < 4; ++im)
#pragma unroll
      for (int in = 0; in < 4; ++in)
        acc[im][in] = __builtin_amdgcn_mfma_f32_16x16x32_bf16(
            fa[im], fb[in], acc[im][in], 0, 0, 0);

    __builtin_amdgcn_sched_barrier(0);
    __builtin_amdgcn_s_barrier();

    if (kk + 2 < nk) {
#pragma unroll
      for (int jj = 0; jj < 2; ++jj) {
        gld16(spA[jj], &As[kk & 1][(wave * 2 + jj) * 512]);
        gld16(spB[jj], &Bs[kk & 1][(wave * 2 + jj) * 512]);
        spA[jj] += 512;
        spB[jj] += 512;
      }
    }
  }

  const int m0w = bm * 128 + wr * 64;
  const int n0w = bn * 128 + wc * 64;

  if (MODE == 0) {
    const float QSCALE = 0.18033688f;  // 0.125 * log2(e)
#pragma unroll
    for (int im = 0; im < 4; ++im) {
      int mbase = m0w + im * 16 + quad * 4;
      int bb = mbase >> 11, tb = mbase & 2047;
#pragma unroll
      for (int in = 0; in < 4; ++in) {
        int n = n0w + in * 16 + l15;
        float bv = bias[n];
        int which = n >> 10;  // uniform within frag
        int h = (n >> 6) & 15;
        int d = n & 63;
        size_t bh_ = (size_t)(bb * 16 + h);
        if (which == 2) {
          // V^T 32-frag: [bh][d/32][t/16][(d%32)+32*((t%16)/8)][t%8]
          size_t base = bh_ * 131072 + (size_t)(d >> 5) * 65536 +
                        (size_t)(tb >> 4) * 512 +
                        (size_t)((d & 31) + 32 * ((tb & 15) >> 3)) * 8 +
                        (tb & 7);
          short4v pk;
#pragma unroll
          for (int r = 0; r < 4; ++r) pk[r] = (short)f2bf(acc[im][in][r] + bv);
          *(short4v*)(Vt + base) = pk;
        } else {
          // Q/K 32-frag: [bh][t/32][d/16][(t%32)+32*((d%16)/8)][d%8]
          size_t base = bh_ * 131072 + (size_t)(tb >> 5) * 2048 +
                        (size_t)(d >> 4) * 512 +
                        (size_t)((tb & 31) + 32 * ((d & 15) >> 3)) * 8 +
                        (d & 7);
          if (which == 0) {
#pragma unroll
            for (int r = 0; r < 4; ++r)
              Qb[base + r * 8] = f2bf((acc[im][in][r] + bv) * QSCALE);
          } else {
#pragma unroll
            for (int r = 0; r < 4; ++r)
              Kb[base + r * 8] = f2bf(acc[im][in][r] + bv);
          }
        }
      }
    }
  } else {
#pragma unroll
    for (int im = 0; im < 4; ++im) {
      int mbase = m0w + im * 16 + quad * 4;
#pragma unroll
      for (int in = 0; in < 4; ++in) {
        int n = n0w + in * 16 + l15;
        float bv = bias[n];
#pragma unroll
        for (int r = 0; r < 4; ++r)
          Cout[(size_t)(mbase + r) * N + n] = acc[im][in][r] + bv;
      }
    }
  }
}

// ---------------- MFMA flash attention (phase-paired, uniform 34 iters) ----
__device__ __forceinline__ void pack_swap(const floatx16& s, short8& lo,
                                          short8& hi) {
  unsigned P0 = cvtpk(s[0], s[1]), P1 = cvtpk(s[2], s[3]);
  unsigned P2 = cvtpk(s[4], s[5]), P3 = cvtpk(s[6], s[7]);
  unsigned P4 = cvtpk(s[8], s[9]), P5 = cvtpk(s[10], s[11]);
  unsigned P6 = cvtpk(s[12], s[13]), P7 = cvtpk(s[14], s[15]);
  uint2v a = __builtin_amdgcn_permlane32_swap(P0, P2, false, false);
  uint2v b = __builtin_amdgcn_permlane32_swap(P1, P3, false, false);
  uint2v c = __builtin_amdgcn_permlane32_swap(P4, P6, false, false);
  uint2v d = __builtin_amdgcn_permlane32_swap(P5, P7, false, false);
  lo = mk8(a.x, b.x, a.y, b.y);
  hi = mk8(c.x, d.x, c.y, d.y);
}

__global__ __launch_bounds__(256, 2) void attn_mfma(
    const unsigned short* __restrict__ Q, const unsigned short* __restrict__ K,
    const unsigned short* __restrict__ Vt, unsigned short* __restrict__ Y) {
  const int b = (int)blockIdx.x;        // 256 blocks (1 per CU)
  const int xcd = b & 7;
  const int bh = xcd * 4 + ((b >> 3) & 3);  // 4 bh per XCD -> KV L2-resident
  const int m = (b >> 5) & 7;               // strip-group 0..7
  const int wave = threadIdx.x >> 6;
  const int lane = threadIdx.x & 63;
  const int l31 = lane & 31, h = lane >> 5;
  const int lofs8 = lane * 8;

  // [buf][16KB]: K tiles (planes 0-7), V d-group0 (8-11), d-group1 (12-15)
  __shared__ __align__(16) unsigned short KV[2][8192];

  const unsigned short* Qb = Q + (size_t)bh * 131072;
  const unsigned short* Kb = K + (size_t)bh * 131072;
  const unsigned short* Vb = Vt + (size_t)bh * 131072;

  auto stage = [&](int buf, int jtN) {
    unsigned short* l = &KV[buf][wave * 2048];
    const unsigned short* g =
        (wave < 2) ? (Kb + (size_t)jtN * 4096 + wave * 2048)
                   : (Vb + (size_t)(wave & 1) * 65536 + (size_t)jtN * 2048);
    g += lofs8;
#pragma unroll
    for (int i = 0; i < 4; ++i) gld16(g + i * 512, l + i * 512);
  };

  const int b_ = bh >> 4, hh = bh & 15;

  // phase 0: strips {4m..4m+3} (ntB = 2m+2); phase 1: mirror {60-4m..63-4m}
  // (ntB = 32-2m). Every block: exactly 34 tile-iterations.
#pragma unroll 1
  for (int ph = 0; ph < 2; ++ph) {
    const int j = ph ? (60 - 4 * m + wave) : (4 * m + wave);
    const int t0 = j * 32;
    const int ntiles = (j >> 1) + 1;      // valid tiles for this wave
    const int ntB = ph ? (32 - 2 * m) : (2 * m + 2);  // block-uniform

    short8 qf[4];
#pragma unroll
    for (int c = 0; c < 4; ++c)
      qf[c] = *(const short8*)(Qb + (size_t)j * 2048 + c * 512 + lofs8);

    floatx16 o0 = (floatx16)0.0f, o1 = (floatx16)0.0f;
    float lp[4] = {0.f, 0.f, 0.f, 0.f};

    stage(0, 0);
    int cur = 0;

    for (int jt = 0; jt < ntB; ++jt) {
      if (jt + 1 < ntB) {
        stage(cur ^ 1, jt + 1);
        vmcnt4();  // this wave's previous-tile loads complete; 4 in flight
      } else {
        vmcnt0();
      }
      __builtin_amdgcn_s_barrier();
      __builtin_amdgcn_sched_barrier(0);

      const unsigned short* Lb = KV[cur];
      short8 kf0[4], kf1[4];
#pragma unroll
      for (int c = 0; c < 4; ++c) {
        kf0[c] = *(const short8*)&Lb[c * 512 + lofs8];
        kf1[c] = *(const short8*)&Lb[2048 + c * 512 + lofs8];
      }

      floatx16 sa0 = (floatx16)0.0f, sa1 = (floatx16)0.0f;
#pragma unroll
      for (int c = 0; c < 4; ++c) {
        sa0 = __builtin_amdgcn_mfma_f32_32x32x16_bf16(kf0[c], qf[c], sa0, 0, 0, 0);
        sa1 = __builtin_amdgcn_mfma_f32_32x32x16_bf16(kf1[c], qf[c], sa1, 0, 0, 0);
      }

      if (jt >= ntiles - 1) {
        // C layout: col=lane&31 (query), row=(r&3)+8*(r>>2)+4*(lane>>5) (key)
#pragma unroll
        for (int r = 0; r < 16; ++r) {
          int row = (r & 3) + 8 * (r >> 2) + 4 * h;
          int key = jt * 64 + row;
          if (key > t0 + l31) sa0[r] = -__builtin_inff();
          if (key + 32 > t0 + l31) sa1[r] = -__builtin_inff();
        }
      }

#pragma unroll
      for (int r = 0; r < 16; ++r) {
        float p0 = exp2f(sa0[r]);
        float p1 = exp2f(sa1[r]);
        sa0[r] = p0;
        sa1[r] = p1;
        lp[r & 3] += p0 + p1;
      }

      short8 pb0, pb1, pb2, pb3;
      pack_swap(sa0, pb0, pb1);
      pack_swap(sa1, pb2, pb3);

      short8 vf0[4], vf1[4];
#pragma unroll
      for (int kc = 0; kc < 4; ++kc) {
        vf0[kc] = *(const short8*)&Lb[4096 + kc * 512 + lofs8];
        vf1[kc] = *(const short8*)&Lb[6144 + kc * 512 + lofs8];
      }

      o0 = __builtin_amdgcn_mfma_f32_32x32x16_bf16(vf0[0], pb0, o0, 0, 0, 0);
      o1 = __builtin_amdgcn_mfma_f32_32x32x16_bf16(vf1[0], pb0, o1, 0, 0, 0);
      o0 = __builtin_amdgcn_mfma_f32_32x32x16_bf16(vf0[1], pb1, o0, 0, 0, 0);
      o1 = __builtin_amdgcn_mfma_f32_32x32x16_bf16(vf1[1], pb1, o1, 0, 0, 0);
      o0 = __builtin_amdgcn_mfma_f32_32x32x16_bf16(vf0[2], pb2, o0, 0, 0, 0);
      o1 = __builtin_amdgcn_mfma_f32_32x32x16_bf16(vf1[2], pb2, o1, 0, 0, 0);
      o0 = __builtin_amdgcn_mfma_f32_32x32x16_bf16(vf0[3], pb3, o0, 0, 0, 0);
      o1 = __builtin_amdgcn_mfma_f32_32x32x16_bf16(vf1[3], pb3, o1, 0, 0, 0);

      __builtin_amdgcn_sched_barrier(0);
      __builtin_amdgcn_s_barrier();  // all waves done reading buf
      cur ^= 1;
    }

    float l_acc = (lp[0] + lp[1]) + (lp[2] + lp[3]);
    l_acc += __shfl_xor(l_acc, 32);
    const float inv = 1.0f / l_acc;

    // epilogue: O^T col=q=l31, row=d within 32-block; y' 16-frag-native
    const int mglob = b_ * 2048 + t0 + l31;
    const size_t mofs = (size_t)(mglob >> 4) * 16384 + (size_t)(mglob & 15) * 8;
#pragma unroll
    for (int db = 0; db < 2; ++db) {
      const floatx16& o = db ? o1 : o0;
#pragma unroll
      for (int g = 0; g < 4; ++g) {
        int d0 = db * 32 + 8 * g + 4 * h;  // regs 4g..4g+3 = d0..d0+3
        int kf0 = hh * 64 + d0;
        size_t ofs = mofs + (size_t)(kf0 >> 3) * 128 + (kf0 & 7);
        short4v pk;
#pragma unroll
        for (int r = 0; r < 4; ++r) pk[r] = (short)f2bf(o[4 * g + r] * inv);
        *(short4v*)(Y + ofs) = pk;
      }
    }
  }
}

extern "C" void kernel_launch(void* const* d_in, const int* in_sizes, int n_in,
                              void* d_out, int out_size, void* d_ws,
                              size_t ws_size, hipStream_t stream) {
  const float* x = (const float*)d_in[0];      // [2,2048,1024]
  const float* Wqkv = (const float*)d_in[1];   // [1024,3072]
  const float* bqkv = (const float*)d_in[2];   // [3072]
  const float* Wproj = (const float*)d_in[3];  // [1024,1024]
  const float* bproj = (const float*)d_in[4];  // [1024]
  float* out = (float*)d_out;                  // [2,2048,1024]

  const int C = 1024;
  const int M = 4096;  // B*T

  char* ws = (char*)d_ws;
  unsigned short* qbuf = (unsigned short*)ws;                  // 8 MiB
  unsigned short* kbuf = (unsigned short*)(ws + 8388608);      // 8 MiB
  unsigned short* vtbuf = (unsigned short*)(ws + 16777216);    // 8 MiB
  unsigned short* ybuf = (unsigned short*)(ws + 25165824);     // 8 MiB y' frag
  unsigned short* xbf = (unsigned short*)(ws + 33554432);      // 8 MiB x' frag
  unsigned short* wqkvF = (unsigned short*)(ws + 41943040);    // 6 MiB
  unsigned short* wprojF = (unsigned short*)(ws + 48234496);   // 2 MiB

  dim3 blk(256);
  pack_all<<<dim3(2048), blk, 0, stream>>>(x, Wqkv, Wproj, xbf, wqkvF, wprojF);
  gemm_lds<0><<<dim3((M / 128) * (3 * C / 128)), blk, 0, stream>>>(
      xbf, wqkvF, bqkv, nullptr, qbuf, kbuf, vtbuf, M, 3 * C, C);
  // 32 bh x 8 strip-groups, phase-paired: 256 uniform blocks (1/CU)
  attn_mfma<<<dim3(256), blk, 0, stream>>>(qbuf, kbuf, vtbuf, ybuf);
  gemm_lds<1><<<dim3((M / 128) * (C / 128)), blk, 0, stream>>>(
      ybuf, wprojF, bproj, out, nullptr, nullptr, nullptr, M, C, C);
}

// Round 9
// 172.203 us; speedup vs baseline: 1.0657x; 1.0657x over previous
//
#include <hip/hip_runtime.h>
#include <math.h>

// CausalSelfAttention: B=2, T=2048, C=1024, H=16, Dh=64. fp32 in/out.
// GEMM operands in 16x16x32 FRAGMENT-NATIVE layouts  F[i/16][k/8][i%16][8]
// Attention operands in 32x32x16 fragment-native layouts:
//   Q/K: [bh][t/32][d/16][(t%32)+32*((d%16)/8)][d%8]
//   V^T: [bh][d/32][t/16][(d%32)+32*((t%16)/8)][t%8]
//  1. pack_all: x -> x' frag; Wqkv/Wproj -> W' frag (transposed)
//  2. gemm_lds<0>: qkv GEMM, BK=32 double-buffered LDS, distance-2 prefetch,
//     raw s_barrier + counted vmcnt (never drains mid-loop) -> Q'/K'/V'
//  3. attn_mfma: flash attention, 32-query strips, 32x32x16 MFMA,
//     block-shared K/V double-buffered in LDS (counted vmcnt prefetch),
//     in-register P via v_cvt_pk_bf16_f32 + permlane32_swap,
//     softmax exp via RAW v_exp_f32 (exp2f's OCML path was ~2x the VALU).
//  4. gemm_lds<1>: proj GEMM -> out fp32

typedef __attribute__((ext_vector_type(8))) short short8;
typedef __attribute__((ext_vector_type(4))) short short4v;
typedef __attribute__((ext_vector_type(4))) float floatx4;
typedef __attribute__((ext_vector_type(16))) float floatx16;
typedef __attribute__((ext_vector_type(2))) unsigned int uint2v;
typedef __attribute__((ext_vector_type(4))) unsigned int uint4v;

__device__ __forceinline__ unsigned short f2bf(float f) {
  unsigned u = __float_as_uint(f);
  return (unsigned short)((u + 0x7fff + ((u >> 16) & 1)) >> 16);
}

// v_cvt_pk_bf16_f32: dst = {lo: bf16(a), hi: bf16(b)} (RNE)
__device__ __forceinline__ unsigned cvtpk(float a, float b) {
  unsigned r;
  asm("v_cvt_pk_bf16_f32 %0, %1, %2" : "=v"(r) : "v"(a), "v"(b));
  return r;
}

// raw v_exp_f32 (2^x). Scores are prescaled and bounded (<=~16); -inf -> 0.
__device__ __forceinline__ float fexp2(float x) {
  float r;
  asm("v_exp_f32 %0, %1" : "=v"(r) : "v"(x));
  return r;
}

__device__ __forceinline__ short8 mk8(unsigned w0, unsigned w1, unsigned w2,
                                      unsigned w3) {
  uint4v v = {w0, w1, w2, w3};
  return __builtin_bit_cast(short8, v);
}

// async global->LDS, 16B per lane; LDS dst is wave-uniform base + lane*16
__device__ __forceinline__ void gld16(const unsigned short* g, unsigned short* l) {
  __builtin_amdgcn_global_load_lds(
      (const __attribute__((address_space(1))) unsigned int*)g,
      (__attribute__((address_space(3))) unsigned int*)l, 16, 0, 0);
}

__device__ __forceinline__ void vmcnt4() {
  asm volatile("s_waitcnt vmcnt(4)" ::: "memory");
}
__device__ __forceinline__ void vmcnt0() {
  asm volatile("s_waitcnt vmcnt(0)" ::: "memory");
}

// ---------------- fused pack kernel ----------------
__device__ __forceinline__ void pack_a_body(const float* __restrict__ in,
                                            unsigned short* __restrict__ out,
                                            int K, int m0, int k0,
                                            unsigned short (*lds)[72], int t) {
  {
    int ml = t >> 2, kl = (t & 3) * 16;
    const float4* p = (const float4*)(in + (size_t)(m0 + ml) * K + k0 + kl);
    unsigned short* q = &lds[ml][kl];
#pragma unroll
    for (int c = 0; c < 4; ++c) {
      float4 v = p[c];
      q[c * 4 + 0] = f2bf(v.x);
      q[c * 4 + 1] = f2bf(v.y);
      q[c * 4 + 2] = f2bf(v.z);
      q[c * 4 + 3] = f2bf(v.w);
    }
  }
  __syncthreads();
  int chunk = t >> 3, sub = t & 7;
  int mt = chunk >> 3, kc = chunk & 7;
  unsigned short tmp[16];
#pragma unroll
  for (int j2 = 0; j2 < 2; ++j2)
#pragma unroll
    for (int j = 0; j < 8; ++j)
      tmp[j2 * 8 + j] = lds[mt * 16 + sub * 2 + j2][kc * 8 + j];
  size_t ofs = ((size_t)(m0 >> 4) + mt) * (16 * (size_t)K) +
               ((size_t)(k0 >> 3) + kc) * 128 + sub * 16;
  *(int4*)(out + ofs) = *(int4*)(tmp);
  *(int4*)(out + ofs + 8) = *(int4*)(tmp + 8);
}

__device__ __forceinline__ void pack_bt_body(const float* __restrict__ in,
                                             unsigned short* __restrict__ out,
                                             int K, int N, int n0, int k0,
                                             unsigned short (*lds)[72], int t) {
  {
    int kl = t >> 2, nl = (t & 3) * 16;
    const float4* p = (const float4*)(in + (size_t)(k0 + kl) * N + n0 + nl);
#pragma unroll
    for (int c = 0; c < 4; ++c) {
      float4 v = p[c];
      lds[nl + c * 4 + 0][kl] = f2bf(v.x);
      lds[nl + c * 4 + 1][kl] = f2bf(v.y);
      lds[nl + c * 4 + 2][kl] = f2bf(v.z);
      lds[nl + c * 4 + 3][kl] = f2bf(v.w);
    }
  }
  __syncthreads();
  int chunk = t >> 3, sub = t & 7;
  int nt = chunk >> 3, kc = chunk & 7;
  unsigned short tmp[16];
#pragma unroll
  for (int j2 = 0; j2 < 2; ++j2)
#pragma unroll
    for (int j = 0; j < 8; ++j)
      tmp[j2 * 8 + j] = lds[nt * 16 + sub * 2 + j2][kc * 8 + j];
  size_t ofs = ((size_t)(n0 >> 4) + nt) * (16 * (size_t)K) +
               ((size_t)(k0 >> 3) + kc) * 128 + sub * 16;
  *(int4*)(out + ofs) = *(int4*)(tmp);
  *(int4*)(out + ofs + 8) = *(int4*)(tmp + 8);
}

__global__ __launch_bounds__(256) void pack_all(
    const float* __restrict__ x, const float* __restrict__ Wqkv,
    const float* __restrict__ Wproj, unsigned short* __restrict__ xbf,
    unsigned short* __restrict__ wqkvF, unsigned short* __restrict__ wprojF) {
  __shared__ __align__(16) unsigned short lds[64][72];
  const int b = blockIdx.x, t = threadIdx.x;
  if (b < 1024) {
    pack_a_body(x, xbf, 1024, (b >> 4) * 64, (b & 15) * 64, lds, t);
  } else if (b < 1792) {
    int b2 = b - 1024;
    pack_bt_body(Wqkv, wqkvF, 1024, 3072, (b2 % 48) * 64, (b2 / 48) * 64, lds, t);
  } else {
    int b3 = b - 1792;
    pack_bt_body(Wproj, wprojF, 1024, 1024, (b3 & 15) * 64, (b3 >> 4) * 64, lds, t);
  }
}

// ------ LDS double-buffered fragment GEMM (BK=32, distance-2 prefetch) ------
template <int MODE>
__global__ __launch_bounds__(256, 3) void gemm_lds(
    const unsigned short* __restrict__ A, const unsigned short* __restrict__ B,
    const float* __restrict__ bias, float* __restrict__ Cout,
    unsigned short* __restrict__ Qb, unsigned short* __restrict__ Kb,
    unsigned short* __restrict__ Vt, int M, int N, int K) {
  const int tid = threadIdx.x;
  const int wave = tid >> 6, lane = tid & 63;
  const int quad = lane >> 4, l15 = lane & 15;
  const int wr = wave >> 1, wc = wave & 1;

  const int nbn = N >> 7;
  const int colsPerX = nbn >> 3;
  const int xcd = (int)(blockIdx.x & 7);
  const int idx = (int)(blockIdx.x >> 3);
  const int bn = xcd * colsPerX + (colsPerX == 1 ? 0 : (idx % colsPerX));
  const int bm = (colsPerX == 1) ? idx : (idx / colsPerX);

  const int mt0 = bm * 8;
  const int nt0 = bn * 8;

  __shared__ __align__(16) unsigned short As[2][4096];
  __shared__ __align__(16) unsigned short Bs[2][4096];

  const unsigned short* spA[2];
  const unsigned short* spB[2];
#pragma unroll
  for (int jj = 0; jj < 2; ++jj) {
    spA[jj] = A + ((size_t)(mt0 + wave * 2 + jj)) * (16 * (size_t)K) + lane * 8;
    spB[jj] = B + ((size_t)(nt0 + wave * 2 + jj)) * (16 * (size_t)K) + lane * 8;
  }

  floatx4 acc[4][4];
#pragma unroll
  for (int i = 0; i < 4; ++i)
#pragma unroll
    for (int j = 0; j < 4; ++j) acc[i][j] = (floatx4)0.0f;

  const int fofs = quad * 128 + l15 * 8;
  const int nk = K >> 5;  // 32

#pragma unroll
  for (int jj = 0; jj < 2; ++jj) {
    gld16(spA[jj], &As[0][(wave * 2 + jj) * 512]);
    gld16(spB[jj], &Bs[0][(wave * 2 + jj) * 512]);
    spA[jj] += 512;
    spB[jj] += 512;
  }
#pragma unroll
  for (int jj = 0; jj < 2; ++jj) {
    gld16(spA[jj], &As[1][(wave * 2 + jj) * 512]);
    gld16(spB[jj], &Bs[1][(wave * 2 + jj) * 512]);
    spA[jj] += 512;
    spB[jj] += 512;
  }

  for (int kk = 0; kk < nk; ++kk) {
    if (kk + 1 < nk) vmcnt4(); else vmcnt0();
    __builtin_amdgcn_s_barrier();
    __builtin_amdgcn_sched_barrier(0);

    const unsigned short* Ab = As[kk & 1];
    const unsigned short* Bb = Bs[kk & 1];
    short8 fa[4], fb[4];
#pragma unroll
    for (int im = 0; im < 4; ++im)
      fa[im] = *(const short8*)&Ab[(wr * 4 + im) * 512 + fofs];
#pragma unroll
    for (int in = 0; in < 4; ++in)
      fb[in] = *(const short8*)&Bb[(wc * 4 + in) * 512 + fofs];
#pragma unroll
    for (int im = 0; im < 4; ++im)
#pragma unroll
      for (int in = 0; in < 4; ++in)
        acc[im][in] = __builtin_amdgcn_mfma_f32_16x16x32_bf16(
            fa[im], fb[in], acc[im][in], 0, 0, 0);

    __builtin_amdgcn_sched_barrier(0);
    __builtin_amdgcn_s_barrier();

    if (kk + 2 < nk) {
#pragma unroll
      for (int jj = 0; jj < 2; ++jj) {
        gld16(spA[jj], &As[kk & 1][(wave * 2 + jj) * 512]);
        gld16(spB[jj], &Bs[kk & 1][(wave * 2 + jj) * 512]);
        spA[jj] += 512;
        spB[jj] += 512;
      }
    }
  }

  const int m0w = bm * 128 + wr * 64;
  const int n0w = bn * 128 + wc * 64;

  if (MODE == 0) {
    const float QSCALE = 0.18033688f;  // 0.125 * log2(e)
#pragma unroll
    for (int im = 0; im < 4; ++im) {
      int mbase = m0w + im * 16 + quad * 4;
      int bb = mbase >> 11, tb = mbase & 2047;
#pragma unroll
      for (int in = 0; in < 4; ++in) {
        int n = n0w + in * 16 + l15;
        float bv = bias[n];
        int which = n >> 10;  // uniform within frag
        int h = (n >> 6) & 15;
        int d = n & 63;
        size_t bh_ = (size_t)(bb * 16 + h);
        if (which == 2) {
          // V^T 32-frag: [bh][d/32][t/16][(d%32)+32*((t%16)/8)][t%8]
          size_t base = bh_ * 131072 + (size_t)(d >> 5) * 65536 +
                        (size_t)(tb >> 4) * 512 +
                        (size_t)((d & 31) + 32 * ((tb & 15) >> 3)) * 8 +
                        (tb & 7);
          short4v pk;
#pragma unroll
          for (int r = 0; r < 4; ++r) pk[r] = (short)f2bf(acc[im][in][r] + bv);
          *(short4v*)(Vt + base) = pk;
        } else {
          // Q/K 32-frag: [bh][t/32][d/16][(t%32)+32*((d%16)/8)][d%8]
          size_t base = bh_ * 131072 + (size_t)(tb >> 5) * 2048 +
                        (size_t)(d >> 4) * 512 +
                        (size_t)((tb & 31) + 32 * ((d & 15) >> 3)) * 8 +
                        (d & 7);
          if (which == 0) {
#pragma unroll
            for (int r = 0; r < 4; ++r)
              Qb[base + r * 8] = f2bf((acc[im][in][r] + bv) * QSCALE);
          } else {
#pragma unroll
            for (int r = 0; r < 4; ++r)
              Kb[base + r * 8] = f2bf(acc[im][in][r] + bv);
          }
        }
      }
    }
  } else {
#pragma unroll
    for (int im = 0; im < 4; ++im) {
      int mbase = m0w + im * 16 + quad * 4;
#pragma unroll
      for (int in = 0; in < 4; ++in) {
        int n = n0w + in * 16 + l15;
        float bv = bias[n];
#pragma unroll
        for (int r = 0; r < 4; ++r)
          Cout[(size_t)(mbase + r) * N + n] = acc[im][in][r] + bv;
      }
    }
  }
}

// ---------------- MFMA flash attention (32q strips, LDS-shared K/V) --------
// Block = 4 waves, wave w owns strip j = m*4+w. 4 strips share every K/V
// tile via LDS (16KB/tile, 16 linear 1KB global_load_lds planes, 4/wave),
// double-buffered, counted vmcnt(4). CU-balanced m mapping (b vs b+256).
__device__ __forceinline__ void pack_swap(const floatx16& s, short8& lo,
                                          short8& hi) {
  unsigned P0 = cvtpk(s[0], s[1]), P1 = cvtpk(s[2], s[3]);
  unsigned P2 = cvtpk(s[4], s[5]), P3 = cvtpk(s[6], s[7]);
  unsigned P4 = cvtpk(s[8], s[9]), P5 = cvtpk(s[10], s[11]);
  unsigned P6 = cvtpk(s[12], s[13]), P7 = cvtpk(s[14], s[15]);
  uint2v a = __builtin_amdgcn_permlane32_swap(P0, P2, false, false);
  uint2v b = __builtin_amdgcn_permlane32_swap(P1, P3, false, false);
  uint2v c = __builtin_amdgcn_permlane32_swap(P4, P6, false, false);
  uint2v d = __builtin_amdgcn_permlane32_swap(P5, P7, false, false);
  lo = mk8(a.x, b.x, a.y, b.y);
  hi = mk8(c.x, d.x, c.y, d.y);
}

__global__ __launch_bounds__(256, 2) void attn_mfma(
    const unsigned short* __restrict__ Q, const unsigned short* __restrict__ K,
    const unsigned short* __restrict__ Vt, unsigned short* __restrict__ Y) {
  const int b = (int)blockIdx.x;        // 512 blocks
  const int xcd = b & 7;
  const int bh = xcd * 4 + ((b >> 3) & 3);  // 4 bh per XCD -> KV L2-resident
  const int k = (b >> 5) & 7;
  // CU-balance attempt: b and b+256 round-robin to the same CU; m sums 15.
  const int m = (b < 256) ? (15 - k) : k;
  const int wave = threadIdx.x >> 6;
  const int lane = threadIdx.x & 63;
  const int j = m * 4 + wave;           // strip 0..63 (32 queries each)
  const int t0 = j * 32;
  const int l31 = lane & 31, h = lane >> 5;
  const int lofs8 = lane * 8;

  // [buf][16KB]: K tiles (planes 0-7), V d-group0 (8-11), d-group1 (12-15)
  __shared__ __align__(16) unsigned short KV[2][8192];

  const unsigned short* Qb = Q + (size_t)bh * 131072;
  const unsigned short* Kb = K + (size_t)bh * 131072;
  const unsigned short* Vb = Vt + (size_t)bh * 131072;

  auto stage = [&](int buf, int jtN) {
    unsigned short* l = &KV[buf][wave * 2048];
    const unsigned short* g =
        (wave < 2) ? (Kb + (size_t)jtN * 4096 + wave * 2048)
                   : (Vb + (size_t)(wave & 1) * 65536 + (size_t)jtN * 2048);
    g += lofs8;
#pragma unroll
    for (int i = 0; i < 4; ++i) gld16(g + i * 512, l + i * 512);
  };

  short8 qf[4];
#pragma unroll
  for (int c = 0; c < 4; ++c)
    qf[c] = *(const short8*)(Qb + (size_t)j * 2048 + c * 512 + lofs8);

  floatx16 o0 = (floatx16)0.0f, o1 = (floatx16)0.0f;
  float lp[4] = {0.f, 0.f, 0.f, 0.f};

  const int ntiles = (j >> 1) + 1;  // valid tiles for this wave
  const int ntB = 2 * m + 2;        // block-uniform loop count

  stage(0, 0);
  int cur = 0;

  for (int jt = 0; jt < ntB; ++jt) {
    if (jt + 1 < ntB) {
      stage(cur ^ 1, jt + 1);
      vmcnt4();  // previous tile's loads (this wave's) complete; 4 in flight
    } else {
      vmcnt0();
    }
    __builtin_amdgcn_s_barrier();
    __builtin_amdgcn_sched_barrier(0);

    const unsigned short* Lb = KV[cur];
    short8 kf0[4], kf1[4];
#pragma unroll
    for (int c = 0; c < 4; ++c) {
      kf0[c] = *(const short8*)&Lb[c * 512 + lofs8];
      kf1[c] = *(const short8*)&Lb[2048 + c * 512 + lofs8];
    }

    floatx16 sa0 = (floatx16)0.0f, sa1 = (floatx16)0.0f;
#pragma unroll
    for (int c = 0; c < 4; ++c) {
      sa0 = __builtin_amdgcn_mfma_f32_32x32x16_bf16(kf0[c], qf[c], sa0, 0, 0, 0);
      sa1 = __builtin_amdgcn_mfma_f32_32x32x16_bf16(kf1[c], qf[c], sa1, 0, 0, 0);
    }

    if (jt >= ntiles - 1) {
      // C layout: col=lane&31 (query), row=(r&3)+8*(r>>2)+4*(lane>>5) (key)
#pragma unroll
      for (int r = 0; r < 16; ++r) {
        int row = (r & 3) + 8 * (r >> 2) + 4 * h;
        int key = jt * 64 + row;
        if (key > t0 + l31) sa0[r] = -__builtin_inff();
        if (key + 32 > t0 + l31) sa1[r] = -__builtin_inff();
      }
    }

#pragma unroll
    for (int r = 0; r < 16; ++r) {
      float p0 = fexp2(sa0[r]);
      float p1 = fexp2(sa1[r]);
      sa0[r] = p0;
      sa1[r] = p1;
      lp[r & 3] += p0 + p1;
    }

    short8 pb0, pb1, pb2, pb3;
    pack_swap(sa0, pb0, pb1);
    pack_swap(sa1, pb2, pb3);

    short8 vf0[4], vf1[4];
#pragma unroll
    for (int kc = 0; kc < 4; ++kc) {
      vf0[kc] = *(const short8*)&Lb[4096 + kc * 512 + lofs8];
      vf1[kc] = *(const short8*)&Lb[6144 + kc * 512 + lofs8];
    }

    o0 = __builtin_amdgcn_mfma_f32_32x32x16_bf16(vf0[0], pb0, o0, 0, 0, 0);
    o1 = __builtin_amdgcn_mfma_f32_32x32x16_bf16(vf1[0], pb0, o1, 0, 0, 0);
    o0 = __builtin_amdgcn_mfma_f32_32x32x16_bf16(vf0[1], pb1, o0, 0, 0, 0);
    o1 = __builtin_amdgcn_mfma_f32_32x32x16_bf16(vf1[1], pb1, o1, 0, 0, 0);
    o0 = __builtin_amdgcn_mfma_f32_32x32x16_bf16(vf0[2], pb2, o0, 0, 0, 0);
    o1 = __builtin_amdgcn_mfma_f32_32x32x16_bf16(vf1[2], pb2, o1, 0, 0, 0);
    o0 = __builtin_amdgcn_mfma_f32_32x32x16_bf16(vf0[3], pb3, o0, 0, 0, 0);
    o1 = __builtin_amdgcn_mfma_f32_32x32x16_bf16(vf1[3], pb3, o1, 0, 0, 0);

    __builtin_amdgcn_sched_barrier(0);
    __builtin_amdgcn_s_barrier();  // all waves done reading buf before restage
    cur ^= 1;
  }

  float l_acc = (lp[0] + lp[1]) + (lp[2] + lp[3]);
  l_acc += __shfl_xor(l_acc, 32);
  const float inv = 1.0f / l_acc;

  // epilogue: O^T col=q=l31, row=d within 32-block; write y' 16-frag-native
  const int b_ = bh >> 4, hh = bh & 15;
  const int mglob = b_ * 2048 + t0 + l31;
  const size_t mofs = (size_t)(mglob >> 4) * 16384 + (size_t)(mglob & 15) * 8;
#pragma unroll
  for (int db = 0; db < 2; ++db) {
    const floatx16& o = db ? o1 : o0;
#pragma unroll
    for (int g = 0; g < 4; ++g) {
      int d0 = db * 32 + 8 * g + 4 * h;  // regs 4g..4g+3 = d0..d0+3
      int kf0 = hh * 64 + d0;
      size_t ofs = mofs + (size_t)(kf0 >> 3) * 128 + (kf0 & 7);
      short4v pk;
#pragma unroll
      for (int r = 0; r < 4; ++r) pk[r] = (short)f2bf(o[4 * g + r] * inv);
      *(short4v*)(Y + ofs) = pk;
    }
  }
}

extern "C" void kernel_launch(void* const* d_in, const int* in_sizes, int n_in,
                              void* d_out, int out_size, void* d_ws,
                              size_t ws_size, hipStream_t stream) {
  const float* x = (const float*)d_in[0];      // [2,2048,1024]
  const float* Wqkv = (const float*)d_in[1];   // [1024,3072]
  const float* bqkv = (const float*)d_in[2];   // [3072]
  const float* Wproj = (const float*)d_in[3];  // [1024,1024]
  const float* bproj = (const float*)d_in[4];  // [1024]
  float* out = (float*)d_out;                  // [2,2048,1024]

  const int C = 1024;
  const int M = 4096;  // B*T

  char* ws = (char*)d_ws;
  unsigned short* qbuf = (unsigned short*)ws;                  // 8 MiB
  unsigned short* kbuf = (unsigned short*)(ws + 8388608);      // 8 MiB
  unsigned short* vtbuf = (unsigned short*)(ws + 16777216);    // 8 MiB
  unsigned short* ybuf = (unsigned short*)(ws + 25165824);     // 8 MiB y' frag
  unsigned short* xbf = (unsigned short*)(ws + 33554432);      // 8 MiB x' frag
  unsigned short* wqkvF = (unsigned short*)(ws + 41943040);    // 6 MiB
  unsigned short* wprojF = (unsigned short*)(ws + 48234496);   // 2 MiB

  dim3 blk(256);
  pack_all<<<dim3(2048), blk, 0, stream>>>(x, Wqkv, Wproj, xbf, wqkvF, wprojF);
  gemm_lds<0><<<dim3((M / 128) * (3 * C / 128)), blk, 0, stream>>>(
      xbf, wqkvF, bqkv, nullptr, qbuf, kbuf, vtbuf, M, 3 * C, C);
  // 32 bh x 16 m-blocks, XCD-decoded + CU-balanced inside
  attn_mfma<<<dim3(512), blk, 0, stream>>>(qbuf, kbuf, vtbuf, ybuf);
  gemm_lds<1><<<dim3((M / 128) * (C / 128)), blk, 0, stream>>>(
      ybuf, wprojF, bproj, out, nullptr, nullptr, nullptr, M, C, C);
}